// Round 17
// baseline (290.375 us; speedup 1.0000x reference)
//
#include <hip/hip_runtime.h>

typedef unsigned short u16;
typedef _Float16 f16;
typedef f16 f16x8 __attribute__((ext_vector_type(8)));
typedef float f32x4 __attribute__((ext_vector_type(4)));

#define B_SZ 8
#define LQ 2048
#define LK 2048
#define HD 1024

__device__ __forceinline__ u16 f32_to_f16(float x) {
  f16 h = (f16)x;
  return __builtin_bit_cast(u16, h);
}
__device__ __forceinline__ float f16_to_f32(u16 h) {
  return (float)__builtin_bit_cast(f16, h);
}

__device__ __forceinline__ void gload_lds16(const void* g, void* l) {
  __builtin_amdgcn_global_load_lds(
      (__attribute__((address_space(1))) void*)(g),
      (__attribute__((address_space(3))) void*)(l), 16, 0, 0);
}

// ---------------------------------------------------------------------------
// fused fp32 -> fp16 convert for q, key, W (three regions, one launch).
// Inputs are read-once: NONTEMPORAL LOADS only (loads are value-safe — inputs
// are never rewritten). All stores cached: nt STORES to validated regions
// proved flaky under the harness poison/replay cycle (R15 post-mortem).
// ---------------------------------------------------------------------------
__global__ __launch_bounds__(256)
void cvt3_k(const f32x4* __restrict__ a, ushort4* __restrict__ oa, int na4,
            const f32x4* __restrict__ b, ushort4* __restrict__ ob, int nb4,
            const f32x4* __restrict__ c, ushort4* __restrict__ oc, int nc4)
{
  int total = na4 + nb4 + nc4;
  int i = blockIdx.x * blockDim.x + threadIdx.x;
  int stride = gridDim.x * blockDim.x;
  for (; i < total; i += stride) {
    const f32x4* src; ushort4* dst; int j;
    if (i < na4)            { src = a; dst = oa; j = i; }
    else if (i < na4 + nb4) { src = b; dst = ob; j = i - na4; }
    else                    { src = c; dst = oc; j = i - na4 - nb4; }
    f32x4 f = __builtin_nontemporal_load(src + j);
    ushort4 h;
    h.x = f32_to_f16(f[0]); h.y = f32_to_f16(f[1]);
    h.z = f32_to_f16(f[2]); h.w = f32_to_f16(f[3]);
    dst[j] = h;   // fp16 re-read by GEMMs: cached store
  }
}

// ---------------------------------------------------------------------------
// V [B][LK][HD] fp32 -> Vt [B][HD][LK] fp16 (32x32 LDS tile transpose).
// V read-once: nontemporal loads. vt store cached.
// ---------------------------------------------------------------------------
__global__ __launch_bounds__(256)
void vtrans_k(const float* __restrict__ V, u16* __restrict__ Vt)
{
  __shared__ float t[32][33];
  int z = blockIdx.z;
  int tx = threadIdx.x, ty = threadIdx.y;
  int h0 = blockIdx.x * 32, k0 = blockIdx.y * 32;
  const float* Vb = V + (size_t)z * LK * HD;
  u16* Vtb = Vt + (size_t)z * HD * LK;
#pragma unroll
  for (int i = 0; i < 4; ++i)
    t[ty + i * 8][tx] = __builtin_nontemporal_load(
        &Vb[(size_t)(k0 + ty + i * 8) * HD + h0 + tx]);
  __syncthreads();
#pragma unroll
  for (int i = 0; i < 4; ++i)
    Vtb[(size_t)(h0 + ty + i * 8) * LK + k0 + tx] = f32_to_f16(t[tx][ty + i * 8]);
}

// ---------------------------------------------------------------------------
// 256x256 B^T GEMM (R9-verified register pipeline + issue-order pin).
//   iter t: stage(t+3)->buf[(t+3)&3]; ds_read(t+1)->Rnxt; sched_barrier;
//           MFMA(Rcur); lgkmcnt(0)+vmcnt(4); barrier.
// Races: stage(t+3) overwrites buf[(t-1)&3]; its frags were consumed at
// iter t-2's lgkmcnt(0) before that iter's barrier. dsread(t+1) needs tile
// t+1 landed: iter t-1's vmcnt(4). Tail iters use vmcnt(0).
// LDS swizzle (0 conflicts, verified R3-R14): stored slot = s ^ ((row>>1)&3)
// on the GLOBAL source, linear LDS dest, undone on ds_read.
// B k-index masked by KB-1 (mask no-op when KA==KB).
// MODE==0: C += bias[n], store fp16. MODE==1: store fp32 batched.
// All stores cached (see R15 post-mortem: nt stores to validated output
// regions are flaky under the harness poison/replay cycle).
// XCD swizzle: bijective (nwg%8==0).
// ---------------------------------------------------------------------------
template<int MODE>
__global__ __launch_bounds__(512, 2)
void gemm256(const u16* __restrict__ A, const u16* __restrict__ Bt,
             const float* __restrict__ bias,
             float* __restrict__ Cf, u16* __restrict__ Ch,
             int N, int KA, int KB, long batchA, long batchB, long batchC)
{
  extern __shared__ u16 smem[];   // 4 bufs x (8192 A + 8192 B) u16 = 128 KB
  const int T = KA >> 5;

  // XCD-aware bijective swizzle
  const int gx = gridDim.x, gy = gridDim.y;
  const int nwg = gx * gy * gridDim.z;
  const int flat = ((int)blockIdx.z * gy + blockIdx.y) * gx + blockIdx.x;
  const int qq = nwg >> 3;
  const int w = (flat & 7) * qq + (flat >> 3);
  const int by = w % gy;
  const int tmp = w / gy;
  const int bx = tmp % gx;
  const int z = tmp / gx;

  const u16* pA = A + (size_t)z * batchA;
  const u16* pB = Bt + (size_t)z * batchB;
  const int kmask = KB - 1;

  const int tid = threadIdx.x;
  const int lane = tid & 63;
  const int wave = tid >> 6;      // 0..7
  const int wr = wave >> 2;       // 0..1  (M)
  const int wc = wave & 3;        // 0..3  (N)
  const int m0 = bx * 256;
  const int n0 = by * 256;
  const int lr = lane & 15;
  const int ls = lane >> 4;

  const int c0 = tid, c1 = tid + 512;
  const int r0 = c0 >> 2, s0 = c0 & 3;
  const int r1 = c1 >> 2, s1 = c1 & 3;
  const int ga0 = ((s0 ^ ((r0 >> 1) & 3)) << 3);
  const int ga1 = ((s1 ^ ((r1 >> 1) & 3)) << 3);

  f32x4 acc[8][4];
  const f32x4 zero4 = {0.f, 0.f, 0.f, 0.f};
#pragma unroll
  for (int i = 0; i < 8; ++i)
#pragma unroll
    for (int j = 0; j < 4; ++j)
      acc[i][j] = zero4;

  const int slot8 = ((ls ^ ((lr >> 1) & 3)) << 3);
  const int baseA = (wr * 128 + lr) * 32 + slot8;
  const int baseB = 8192 + (wc * 64 + lr) * 32 + slot8;

  auto stage = [&](int t) {
    u16* b = smem + (t & 3) * 16384;
    const int kt = t * 32;
    const int ktb = kt & kmask;
    gload_lds16(pA + (size_t)(m0 + r0) * KA + kt + ga0, b + c0 * 8);
    gload_lds16(pA + (size_t)(m0 + r1) * KA + kt + ga1, b + c1 * 8);
    gload_lds16(pB + (size_t)(n0 + r0) * KB + ktb + ga0, b + 8192 + c0 * 8);
    gload_lds16(pB + (size_t)(n0 + r1) * KB + ktb + ga1, b + 8192 + c1 * 8);
  };

  auto dsread = [&](int t, f16x8* Af, f16x8* Bf) {
    const u16* cb = smem + (t & 3) * 16384;
#pragma unroll
    for (int mi = 0; mi < 8; ++mi)
      Af[mi] = *(const f16x8*)(cb + baseA + mi * 512);
#pragma unroll
    for (int ni = 0; ni < 4; ++ni)
      Bf[ni] = *(const f16x8*)(cb + baseB + ni * 512);
  };

  auto domfma = [&](f16x8* Af, f16x8* Bf) {
    __builtin_amdgcn_s_setprio(1);
#pragma unroll
    for (int ni = 0; ni < 4; ++ni)
#pragma unroll
      for (int mi = 0; mi < 8; ++mi)
        acc[mi][ni] = __builtin_amdgcn_mfma_f32_16x16x32_f16(Af[mi], Bf[ni], acc[mi][ni], 0, 0, 0);
    __builtin_amdgcn_s_setprio(0);
  };

  auto body = [&](int t, f16x8* cA, f16x8* cB, f16x8* nA, f16x8* nB, bool drain) {
    if (t + 3 < T) stage(t + 3);
    dsread(t + 1, nA, nB);
    __builtin_amdgcn_sched_barrier(0);
    domfma(cA, cB);
    if (drain) asm volatile("s_waitcnt vmcnt(0) lgkmcnt(0)" ::: "memory");
    else       asm volatile("s_waitcnt vmcnt(4) lgkmcnt(0)" ::: "memory");
    __builtin_amdgcn_sched_barrier(0);
    __builtin_amdgcn_s_barrier();
    __builtin_amdgcn_sched_barrier(0);
  };

  f16x8 RAa[8], RAb[4], RBa[8], RBb[4];

  // prologue: tiles 0,1,2 staged; wait 0,1 landed (tile 2 stays in flight)
  stage(0); stage(1); stage(2);
  asm volatile("s_waitcnt vmcnt(4)" ::: "memory");
  __builtin_amdgcn_s_barrier();
  __builtin_amdgcn_sched_barrier(0);
  dsread(0, RAa, RAb);

  for (int t = 0; t + 4 < T; t += 2) {
    body(t,     RAa, RAb, RBa, RBb, false);
    body(t + 1, RBa, RBb, RAa, RAb, false);
  }
  body(T - 4, RAa, RAb, RBa, RBb, false);
  body(T - 3, RBa, RBb, RAa, RAb, true);   // drain: last tile must land
  body(T - 2, RAa, RAb, RBa, RBb, true);
  domfma(RBa, RBb);                        // tile T-1

  // epilogue: C/D layout: col = lane&15 (lr), row = ls*4 + r within frag
#pragma unroll
  for (int mi = 0; mi < 8; ++mi) {
#pragma unroll
    for (int ni = 0; ni < 4; ++ni) {
#pragma unroll
      for (int r = 0; r < 4; ++r) {
        int row = m0 + wr * 128 + mi * 16 + ls * 4 + r;
        int col = n0 + wc * 64 + ni * 16 + lr;
        float v = acc[mi][ni][r];
        if (MODE == 0) {
          v += bias[col];
          Ch[(size_t)row * N + col] = f32_to_f16(v);
        } else {
          Cf[(size_t)z * batchC + (size_t)row * N + col] = v;
        }
      }
    }
  }
}

// ---------------------------------------------------------------------------
// row softmax over Lk=2048, in place (fp32) + fp16 copy. 1 block (256t) / row.
// All stores cached.
// ---------------------------------------------------------------------------
__global__ __launch_bounds__(256)
void softmax_k(float* __restrict__ sc, u16* __restrict__ pf)
{
  __shared__ float redm[4], reds[4];
  size_t row = blockIdx.x;
  float* rp = sc + row * (size_t)LK;
  int tid = threadIdx.x;
  int lane = tid & 63, wv = tid >> 6;

  f32x4 v0 = *(const f32x4*)(rp + tid * 8);
  f32x4 v1 = *(const f32x4*)(rp + tid * 8 + 4);

  float m = fmaxf(fmaxf(fmaxf(v0[0], v0[1]), fmaxf(v0[2], v0[3])),
                  fmaxf(fmaxf(v1[0], v1[1]), fmaxf(v1[2], v1[3])));
#pragma unroll
  for (int off = 32; off > 0; off >>= 1)
    m = fmaxf(m, __shfl_xor(m, off));
  if (lane == 0) redm[wv] = m;
  __syncthreads();
  m = fmaxf(fmaxf(redm[0], redm[1]), fmaxf(redm[2], redm[3]));

  float e[8];
  e[0] = __expf(v0[0] - m); e[1] = __expf(v0[1] - m);
  e[2] = __expf(v0[2] - m); e[3] = __expf(v0[3] - m);
  e[4] = __expf(v1[0] - m); e[5] = __expf(v1[1] - m);
  e[6] = __expf(v1[2] - m); e[7] = __expf(v1[3] - m);
  float s = ((e[0] + e[1]) + (e[2] + e[3])) + ((e[4] + e[5]) + (e[6] + e[7]));
#pragma unroll
  for (int off = 32; off > 0; off >>= 1)
    s += __shfl_xor(s, off);
  if (lane == 0) reds[wv] = s;
  __syncthreads();
  s = (reds[0] + reds[1]) + (reds[2] + reds[3]);

  float inv = 1.0f / s;
  f32x4 p0 = {e[0] * inv, e[1] * inv, e[2] * inv, e[3] * inv};
  f32x4 p1 = {e[4] * inv, e[5] * inv, e[6] * inv, e[7] * inv};
  *(f32x4*)(rp + tid * 8) = p0;
  *(f32x4*)(rp + tid * 8 + 4) = p1;

  u16* pb = pf + row * (size_t)LK + tid * 8;
  ushort4 h0, h1;
  h0.x = f32_to_f16(p0[0]); h0.y = f32_to_f16(p0[1]);
  h0.z = f32_to_f16(p0[2]); h0.w = f32_to_f16(p0[3]);
  h1.x = f32_to_f16(p1[0]); h1.y = f32_to_f16(p1[1]);
  h1.z = f32_to_f16(p1[2]); h1.w = f32_to_f16(p1[3]);
  *(ushort4*)(pb) = h0;
  *(ushort4*)(pb + 4) = h1;
}

// ---------------------------------------------------------------------------
extern "C" void kernel_launch(void* const* d_in, const int* in_sizes, int n_in,
                              void* d_out, int out_size, void* d_ws, size_t ws_size,
                              hipStream_t stream)
{
  const float* q  = (const float*)d_in[0];
  const float* ky = (const float*)d_in[1];
  const float* vv = (const float*)d_in[2];
  const float* Ww = (const float*)d_in[3];
  const float* Wb = (const float*)d_in[4];
  float* out   = (float*)d_out;                       // [8,2048,1024]
  float* pattn = out + (size_t)B_SZ * LQ * HD;        // [8,2048,2048]

  char* ws = (char*)d_ws;
  u16* qh = (u16*)(ws);                               // q fp16, 32 MB
  u16* kh = (u16*)(ws + 33554432);                    // key fp16, 32 MB
  u16* wh = (u16*)(ws + 67108864);                    // W fp16, 2 MB
  u16* vt = (u16*)(ws + 69206016);                    // V^T fp16, 32 MB
  u16* qp = (u16*)(ws + 102760448);                   // q_proj fp16, 32 MB
  u16* pf = (u16*)(ws);                               // p fp16, 67 MB (reuses
                                                      // qh+kh+wh, dead by then)

  const int nq4 = (int)((size_t)B_SZ * LQ * HD / 4);  // 4,194,304
  const int nw4 = HD * HD / 4;                        // 262,144

  cvt3_k<<<4096, 256, 0, stream>>>(
      (const f32x4*)q, (ushort4*)qh, nq4,
      (const f32x4*)ky, (ushort4*)kh, nq4,
      (const f32x4*)Ww, (ushort4*)wh, nw4);
  vtrans_k<<<dim3(HD / 32, LK / 32, B_SZ), dim3(32, 8), 0, stream>>>(vv, vt);

  // GEMM1: q_proj = q @ W^T + b  (single fp16, K=1024) -> fp16 qp
  gemm256<0><<<dim3(64, 4, 1), 512, 131072, stream>>>(
      qh, wh, Wb, nullptr, qp,
      HD, 1024, HD, 0, 0, 0);

  // GEMM2: scores = q_proj @ key^T  (single fp16, K=1024) -> fp32 p_attn ws
  gemm256<1><<<dim3(8, 8, 8), 512, 131072, stream>>>(
      qp, kh, nullptr, pattn, nullptr,
      LK, 1024, HD, (long)LQ * HD, (long)LK * HD, (long)LQ * LK);

  // softmax rows, in place + fp16 copy for PV
  softmax_k<<<B_SZ * LQ, 256, 0, stream>>>(pattn, pf);

  // GEMM3: out = p @ V   (Vt is [HD][LK] per batch)
  gemm256<1><<<dim3(8, 4, 8), 512, 131072, stream>>>(
      pf, vt, nullptr, out, nullptr,
      HD, 2048, LK, (long)LQ * LK, (long)HD * LK, (long)LQ * HD);
}

// Round 18
// 283.457 us; speedup vs baseline: 1.0244x; 1.0244x over previous
//
#include <hip/hip_runtime.h>

typedef unsigned short u16;
typedef _Float16 f16;
typedef f16 f16x8 __attribute__((ext_vector_type(8)));
typedef float f32x4 __attribute__((ext_vector_type(4)));

#define B_SZ 8
#define LQ 2048
#define LK 2048
#define HD 1024

__device__ __forceinline__ u16 f32_to_f16(float x) {
  f16 h = (f16)x;
  return __builtin_bit_cast(u16, h);
}
__device__ __forceinline__ float f16_to_f32(u16 h) {
  return (float)__builtin_bit_cast(f16, h);
}

__device__ __forceinline__ void gload_lds16(const void* g, void* l) {
  __builtin_amdgcn_global_load_lds(
      (__attribute__((address_space(1))) void*)(g),
      (__attribute__((address_space(3))) void*)(l), 16, 0, 0);
}

// ---------------------------------------------------------------------------
// fused fp32 -> fp16 convert for q, key, W (three regions, one launch).
// Inputs are read-once: NONTEMPORAL LOADS only (loads are value-safe — inputs
// are never rewritten). All stores cached: nt STORES to validated regions
// proved flaky under the harness poison/replay cycle (R15 post-mortem).
// ---------------------------------------------------------------------------
__global__ __launch_bounds__(256)
void cvt3_k(const f32x4* __restrict__ a, ushort4* __restrict__ oa, int na4,
            const f32x4* __restrict__ b, ushort4* __restrict__ ob, int nb4,
            const f32x4* __restrict__ c, ushort4* __restrict__ oc, int nc4)
{
  int total = na4 + nb4 + nc4;
  int i = blockIdx.x * blockDim.x + threadIdx.x;
  int stride = gridDim.x * blockDim.x;
  for (; i < total; i += stride) {
    const f32x4* src; ushort4* dst; int j;
    if (i < na4)            { src = a; dst = oa; j = i; }
    else if (i < na4 + nb4) { src = b; dst = ob; j = i - na4; }
    else                    { src = c; dst = oc; j = i - na4 - nb4; }
    f32x4 f = __builtin_nontemporal_load(src + j);
    ushort4 h;
    h.x = f32_to_f16(f[0]); h.y = f32_to_f16(f[1]);
    h.z = f32_to_f16(f[2]); h.w = f32_to_f16(f[3]);
    dst[j] = h;   // fp16 re-read by GEMMs: cached store
  }
}

// ---------------------------------------------------------------------------
// V [B][LK][HD] fp32 -> Vt [B][HD][LK] fp16 (32x32 LDS tile transpose).
// V read-once: nontemporal loads. vt store cached. Runs AFTER softmax so
// vt (33 MB) + pf (67 MB) are both L3-resident when GEMM3 reads them
// (running vtrans first guaranteed eviction by ~400 MB of GEMM traffic).
// ---------------------------------------------------------------------------
__global__ __launch_bounds__(256)
void vtrans_k(const float* __restrict__ V, u16* __restrict__ Vt)
{
  __shared__ float t[32][33];
  int z = blockIdx.z;
  int tx = threadIdx.x, ty = threadIdx.y;
  int h0 = blockIdx.x * 32, k0 = blockIdx.y * 32;
  const float* Vb = V + (size_t)z * LK * HD;
  u16* Vtb = Vt + (size_t)z * HD * LK;
#pragma unroll
  for (int i = 0; i < 4; ++i)
    t[ty + i * 8][tx] = __builtin_nontemporal_load(
        &Vb[(size_t)(k0 + ty + i * 8) * HD + h0 + tx]);
  __syncthreads();
#pragma unroll
  for (int i = 0; i < 4; ++i)
    Vtb[(size_t)(h0 + ty + i * 8) * LK + k0 + tx] = f32_to_f16(t[tx][ty + i * 8]);
}

// ---------------------------------------------------------------------------
// 256x256 B^T GEMM (R9-verified register pipeline + issue-order pin).
//   iter t: stage(t+3)->buf[(t+3)&3]; ds_read(t+1)->Rnxt; sched_barrier;
//           MFMA(Rcur); lgkmcnt(0)+vmcnt(4); barrier.
// Races: stage(t+3) overwrites buf[(t-1)&3]; its frags were consumed at
// iter t-2's lgkmcnt(0) before that iter's barrier. dsread(t+1) needs tile
// t+1 landed: iter t-1's vmcnt(4). Tail iters use vmcnt(0).
// LDS swizzle (0 conflicts, verified R3-R16): stored slot = s ^ ((row>>1)&3)
// on the GLOBAL source, linear LDS dest, undone on ds_read.
// B k-index masked by KB-1 (mask no-op when KA==KB).
// MODE==0: C += bias[n], store fp16. MODE==1: store fp32 batched.
// All stores cached (R15 post-mortem: nt stores to validated output
// regions are flaky under the harness poison/replay cycle).
// XCD swizzle: bijective (nwg%8==0).
// ---------------------------------------------------------------------------
template<int MODE>
__global__ __launch_bounds__(512, 2)
void gemm256(const u16* __restrict__ A, const u16* __restrict__ Bt,
             const float* __restrict__ bias,
             float* __restrict__ Cf, u16* __restrict__ Ch,
             int N, int KA, int KB, long batchA, long batchB, long batchC)
{
  extern __shared__ u16 smem[];   // 4 bufs x (8192 A + 8192 B) u16 = 128 KB
  const int T = KA >> 5;

  // XCD-aware bijective swizzle
  const int gx = gridDim.x, gy = gridDim.y;
  const int nwg = gx * gy * gridDim.z;
  const int flat = ((int)blockIdx.z * gy + blockIdx.y) * gx + blockIdx.x;
  const int qq = nwg >> 3;
  const int w = (flat & 7) * qq + (flat >> 3);
  const int by = w % gy;
  const int tmp = w / gy;
  const int bx = tmp % gx;
  const int z = tmp / gx;

  const u16* pA = A + (size_t)z * batchA;
  const u16* pB = Bt + (size_t)z * batchB;
  const int kmask = KB - 1;

  const int tid = threadIdx.x;
  const int lane = tid & 63;
  const int wave = tid >> 6;      // 0..7
  const int wr = wave >> 2;       // 0..1  (M)
  const int wc = wave & 3;        // 0..3  (N)
  const int m0 = bx * 256;
  const int n0 = by * 256;
  const int lr = lane & 15;
  const int ls = lane >> 4;

  const int c0 = tid, c1 = tid + 512;
  const int r0 = c0 >> 2, s0 = c0 & 3;
  const int r1 = c1 >> 2, s1 = c1 & 3;
  const int ga0 = ((s0 ^ ((r0 >> 1) & 3)) << 3);
  const int ga1 = ((s1 ^ ((r1 >> 1) & 3)) << 3);

  f32x4 acc[8][4];
  const f32x4 zero4 = {0.f, 0.f, 0.f, 0.f};
#pragma unroll
  for (int i = 0; i < 8; ++i)
#pragma unroll
    for (int j = 0; j < 4; ++j)
      acc[i][j] = zero4;

  const int slot8 = ((ls ^ ((lr >> 1) & 3)) << 3);
  const int baseA = (wr * 128 + lr) * 32 + slot8;
  const int baseB = 8192 + (wc * 64 + lr) * 32 + slot8;

  auto stage = [&](int t) {
    u16* b = smem + (t & 3) * 16384;
    const int kt = t * 32;
    const int ktb = kt & kmask;
    gload_lds16(pA + (size_t)(m0 + r0) * KA + kt + ga0, b + c0 * 8);
    gload_lds16(pA + (size_t)(m0 + r1) * KA + kt + ga1, b + c1 * 8);
    gload_lds16(pB + (size_t)(n0 + r0) * KB + ktb + ga0, b + 8192 + c0 * 8);
    gload_lds16(pB + (size_t)(n0 + r1) * KB + ktb + ga1, b + 8192 + c1 * 8);
  };

  auto dsread = [&](int t, f16x8* Af, f16x8* Bf) {
    const u16* cb = smem + (t & 3) * 16384;
#pragma unroll
    for (int mi = 0; mi < 8; ++mi)
      Af[mi] = *(const f16x8*)(cb + baseA + mi * 512);
#pragma unroll
    for (int ni = 0; ni < 4; ++ni)
      Bf[ni] = *(const f16x8*)(cb + baseB + ni * 512);
  };

  auto domfma = [&](f16x8* Af, f16x8* Bf) {
    __builtin_amdgcn_s_setprio(1);
#pragma unroll
    for (int ni = 0; ni < 4; ++ni)
#pragma unroll
      for (int mi = 0; mi < 8; ++mi)
        acc[mi][ni] = __builtin_amdgcn_mfma_f32_16x16x32_f16(Af[mi], Bf[ni], acc[mi][ni], 0, 0, 0);
    __builtin_amdgcn_s_setprio(0);
  };

  auto body = [&](int t, f16x8* cA, f16x8* cB, f16x8* nA, f16x8* nB, bool drain) {
    if (t + 3 < T) stage(t + 3);
    dsread(t + 1, nA, nB);
    __builtin_amdgcn_sched_barrier(0);
    domfma(cA, cB);
    if (drain) asm volatile("s_waitcnt vmcnt(0) lgkmcnt(0)" ::: "memory");
    else       asm volatile("s_waitcnt vmcnt(4) lgkmcnt(0)" ::: "memory");
    __builtin_amdgcn_sched_barrier(0);
    __builtin_amdgcn_s_barrier();
    __builtin_amdgcn_sched_barrier(0);
  };

  f16x8 RAa[8], RAb[4], RBa[8], RBb[4];

  // prologue: tiles 0,1,2 staged; wait 0,1 landed (tile 2 stays in flight)
  stage(0); stage(1); stage(2);
  asm volatile("s_waitcnt vmcnt(4)" ::: "memory");
  __builtin_amdgcn_s_barrier();
  __builtin_amdgcn_sched_barrier(0);
  dsread(0, RAa, RAb);

  for (int t = 0; t + 4 < T; t += 2) {
    body(t,     RAa, RAb, RBa, RBb, false);
    body(t + 1, RBa, RBb, RAa, RAb, false);
  }
  body(T - 4, RAa, RAb, RBa, RBb, false);
  body(T - 3, RBa, RBb, RAa, RAb, true);   // drain: last tile must land
  body(T - 2, RAa, RAb, RBa, RBb, true);
  domfma(RBa, RBb);                        // tile T-1

  // epilogue: C/D layout: col = lane&15 (lr), row = ls*4 + r within frag
#pragma unroll
  for (int mi = 0; mi < 8; ++mi) {
#pragma unroll
    for (int ni = 0; ni < 4; ++ni) {
#pragma unroll
      for (int r = 0; r < 4; ++r) {
        int row = m0 + wr * 128 + mi * 16 + ls * 4 + r;
        int col = n0 + wc * 64 + ni * 16 + lr;
        float v = acc[mi][ni][r];
        if (MODE == 0) {
          v += bias[col];
          Ch[(size_t)row * N + col] = f32_to_f16(v);
        } else {
          Cf[(size_t)z * batchC + (size_t)row * N + col] = v;
        }
      }
    }
  }
}

// ---------------------------------------------------------------------------
// row softmax over Lk=2048, in place (fp32) + fp16 copy. 1 block (256t) / row.
// All stores cached.
// ---------------------------------------------------------------------------
__global__ __launch_bounds__(256)
void softmax_k(float* __restrict__ sc, u16* __restrict__ pf)
{
  __shared__ float redm[4], reds[4];
  size_t row = blockIdx.x;
  float* rp = sc + row * (size_t)LK;
  int tid = threadIdx.x;
  int lane = tid & 63, wv = tid >> 6;

  f32x4 v0 = *(const f32x4*)(rp + tid * 8);
  f32x4 v1 = *(const f32x4*)(rp + tid * 8 + 4);

  float m = fmaxf(fmaxf(fmaxf(v0[0], v0[1]), fmaxf(v0[2], v0[3])),
                  fmaxf(fmaxf(v1[0], v1[1]), fmaxf(v1[2], v1[3])));
#pragma unroll
  for (int off = 32; off > 0; off >>= 1)
    m = fmaxf(m, __shfl_xor(m, off));
  if (lane == 0) redm[wv] = m;
  __syncthreads();
  m = fmaxf(fmaxf(redm[0], redm[1]), fmaxf(redm[2], redm[3]));

  float e[8];
  e[0] = __expf(v0[0] - m); e[1] = __expf(v0[1] - m);
  e[2] = __expf(v0[2] - m); e[3] = __expf(v0[3] - m);
  e[4] = __expf(v1[0] - m); e[5] = __expf(v1[1] - m);
  e[6] = __expf(v1[2] - m); e[7] = __expf(v1[3] - m);
  float s = ((e[0] + e[1]) + (e[2] + e[3])) + ((e[4] + e[5]) + (e[6] + e[7]));
#pragma unroll
  for (int off = 32; off > 0; off >>= 1)
    s += __shfl_xor(s, off);
  if (lane == 0) reds[wv] = s;
  __syncthreads();
  s = (reds[0] + reds[1]) + (reds[2] + reds[3]);

  float inv = 1.0f / s;
  f32x4 p0 = {e[0] * inv, e[1] * inv, e[2] * inv, e[3] * inv};
  f32x4 p1 = {e[4] * inv, e[5] * inv, e[6] * inv, e[7] * inv};
  *(f32x4*)(rp + tid * 8) = p0;
  *(f32x4*)(rp + tid * 8 + 4) = p1;

  u16* pb = pf + row * (size_t)LK + tid * 8;
  ushort4 h0, h1;
  h0.x = f32_to_f16(p0[0]); h0.y = f32_to_f16(p0[1]);
  h0.z = f32_to_f16(p0[2]); h0.w = f32_to_f16(p0[3]);
  h1.x = f32_to_f16(p1[0]); h1.y = f32_to_f16(p1[1]);
  h1.z = f32_to_f16(p1[2]); h1.w = f32_to_f16(p1[3]);
  *(ushort4*)(pb) = h0;
  *(ushort4*)(pb + 4) = h1;
}

// ---------------------------------------------------------------------------
extern "C" void kernel_launch(void* const* d_in, const int* in_sizes, int n_in,
                              void* d_out, int out_size, void* d_ws, size_t ws_size,
                              hipStream_t stream)
{
  const float* q  = (const float*)d_in[0];
  const float* ky = (const float*)d_in[1];
  const float* vv = (const float*)d_in[2];
  const float* Ww = (const float*)d_in[3];
  const float* Wb = (const float*)d_in[4];
  float* out   = (float*)d_out;                       // [8,2048,1024]
  float* pattn = out + (size_t)B_SZ * LQ * HD;        // [8,2048,2048]

  char* ws = (char*)d_ws;
  u16* qh = (u16*)(ws);                               // q fp16, 32 MB
  u16* kh = (u16*)(ws + 33554432);                    // key fp16, 32 MB
  u16* wh = (u16*)(ws + 67108864);                    // W fp16, 2 MB
  u16* vt = (u16*)(ws + 69206016);                    // V^T fp16, 32 MB
  u16* qp = (u16*)(ws + 102760448);                   // q_proj fp16, 32 MB
  u16* pf = (u16*)(ws);                               // p fp16, 67 MB (reuses
                                                      // qh+kh+wh, dead by then)

  const int nq4 = (int)((size_t)B_SZ * LQ * HD / 4);  // 4,194,304
  const int nw4 = HD * HD / 4;                        // 262,144

  cvt3_k<<<4096, 256, 0, stream>>>(
      (const f32x4*)q, (ushort4*)qh, nq4,
      (const f32x4*)ky, (ushort4*)kh, nq4,
      (const f32x4*)Ww, (ushort4*)wh, nw4);

  // GEMM1: q_proj = q @ W^T + b  (single fp16, K=1024) -> fp16 qp
  gemm256<0><<<dim3(64, 4, 1), 512, 131072, stream>>>(
      qh, wh, Wb, nullptr, qp,
      HD, 1024, HD, 0, 0, 0);

  // GEMM2: scores = q_proj @ key^T  (single fp16, K=1024) -> fp32 p_attn ws
  gemm256<1><<<dim3(8, 8, 8), 512, 131072, stream>>>(
      qp, kh, nullptr, pattn, nullptr,
      LK, 1024, HD, (long)LQ * HD, (long)LK * HD, (long)LQ * LK);

  // softmax rows, in place + fp16 copy for PV
  softmax_k<<<B_SZ * LQ, 256, 0, stream>>>(pattn, pf);

  // V transpose AFTER softmax: vt + pf both L3-hot for GEMM3
  vtrans_k<<<dim3(HD / 32, LK / 32, B_SZ), dim3(32, 8), 0, stream>>>(vv, vt);

  // GEMM3: out = p @ V   (Vt is [HD][LK] per batch)
  gemm256<1><<<dim3(8, 4, 8), 512, 131072, stream>>>(
      pf, vt, nullptr, out, nullptr,
      HD, 2048, LK, (long)LQ * LK, (long)HD * LK, (long)LQ * HD);
}